// Round 18
// baseline (1042.087 us; speedup 1.0000x reference)
//
#include <hip/hip_runtime.h>
#include <cmath>

#define BB 2
#define LL 4096
#define DM 1024
#define DI 2048
#define NS 64
static constexpr float EPSF  = 1.1920928955078125e-07f; // float32 eps
static constexpr float LOG2E = 1.4426950408889634f;

typedef unsigned short u16;
typedef __attribute__((ext_vector_type(4))) unsigned short u16x4;
typedef __attribute__((ext_vector_type(8))) short bf16x8;
typedef __attribute__((ext_vector_type(4))) float f32x4;

__device__ __forceinline__ u16 f2bf(float f){
    unsigned u = __float_as_uint(f);
    return (u16)((u + 0x7fffu + ((u >> 16) & 1u)) >> 16);   // RNE
}
__device__ __forceinline__ float bf2f(u16 h){ return __uint_as_float(((unsigned)h) << 16); }
__device__ __forceinline__ void gload16(const void* g, void* l){
    __builtin_amdgcn_global_load_lds((const __attribute__((address_space(1))) void*)g,
                                     (__attribute__((address_space(3))) void*)l, 16, 0, 0);
}

// =====================================================================
// Fused fp32->bf16 convert. ip segment is PERMUTED: W'[r] interleaves
// x-rows and gate-rows in 32-row groups (gate pairing in gemm256<0>).
// Segments (vec4 units): x 2097152 | ip 1048576 | dtw 1048576 |
//   B_w 32768 | C_w 32768 | ow 524288
// =====================================================================
__global__ __launch_bounds__(256)
void cvt_all(const float* __restrict__ s0, const float* __restrict__ s1,
             const float* __restrict__ s2, const float* __restrict__ s3,
             const float* __restrict__ s4, const float* __restrict__ s5,
             u16* __restrict__ d0, u16* __restrict__ d1, u16* __restrict__ d2,
             u16* __restrict__ d3, u16* __restrict__ d4, u16* __restrict__ d5)
{
    size_t v = (size_t)blockIdx.x * 256 + threadIdx.x;   // vec4 index
    const float* src; u16* dst; size_t off;
    int seg;
    if      (v < 2097152u){ src=s0; dst=d0; off=v; seg=0; }
    else if (v < 3145728u){ src=s1; dst=d1; off=v-2097152u; seg=1; }
    else if (v < 4194304u){ src=s2; dst=d2; off=v-3145728u; seg=2; }
    else if (v < 4227072u){ src=s3; dst=d3; off=v-4194304u; seg=3; }
    else if (v < 4259840u){ src=s4; dst=d4; off=v-4227072u; seg=4; }
    else                  { src=s5; dst=d5; off=v-4259840u; seg=5; }
    size_t i = off*4;
    size_t isrc = i;
    if (seg == 1){
        // dst row r -> src row s (32-row x/gate interleave)
        size_t r = i >> 10, c = i & 1023;
        size_t g = r >> 6, w6 = r & 63;
        size_t s = (w6 < 32) ? (g*32 + w6) : (2048 + g*32 + (w6 - 32));
        isrc = s*1024 + c;
    }
    float4 x = *(const float4*)(src+isrc);
    u16x4 o; o[0]=f2bf(x.x); o[1]=f2bf(x.y); o[2]=f2bf(x.z); o[3]=f2bf(x.w);
    *(u16x4*)(dst+i) = o;
}

// =====================================================================
// 256x256 / BK=64 deep-pipelined GEMM (T2 swizzle, T3+T4 counted vmcnt,
// T5 setprio, raw s_barrier). 512 thr = 8 waves as 8M x 1N.
// EPI 0: silu-gate (W' interleaved) -> bf16 xin [M, N/2]
// EPI 1: n0<2048: softplus+bias -> bf16 dtT[b][col][l] time-minor;
//        n0==2048: cols<2176 -> BC f32 interleaved [t][n2][{B,C}] (bcout);
//        cols>=2176: pad, skip (operand garbage is finite, never stored)
// EPI 2: plain f32 out [M, N]
// =====================================================================
template<int EPI>
__global__ __launch_bounds__(512)
void gemm256(const u16* __restrict__ A, const u16* __restrict__ W,
             const float* __restrict__ bias, void* __restrict__ outv,
             float* __restrict__ bcout, int M, int N, int K)
{
    __shared__ u16 Adb[2][256*64];
    __shared__ u16 Bdb[2][256*64];
    const int tid  = threadIdx.x;
    const int lane = tid & 63;
    const int w    = tid >> 6;
    const int n0 = blockIdx.x * 256;
    const int m0 = blockIdx.y * 256;
    const int NT = K >> 6;

    f32x4 acc[2][16];
    #pragma unroll
    for (int mf=0; mf<2; mf++)
        #pragma unroll
        for (int nf=0; nf<16; nf++)
            #pragma unroll
            for (int r=0;r<4;r++) acc[mf][nf][r] = 0.f;

    auto stageA = [&](int kt, int buf){
        const int k0 = kt << 6;
        #pragma unroll
        for (int i=0;i<4;i++){
            const int s = i*512 + tid;
            const int row = s >> 3;
            const int q = (s & 7) ^ (row & 7);
            gload16(A + (size_t)(m0+row)*K + k0 + q*8, &Adb[buf][s*8]);
        }
    };
    auto stageBh = [&](int kt, int nh, int buf){
        const int k0 = kt << 6;
        #pragma unroll
        for (int i=0;i<2;i++){
            const int s = i*512 + tid;
            const int row = nh*128 + (s >> 3);
            const int q = (s & 7) ^ (row & 7);
            gload16(W + (size_t)(n0+row)*K + k0 + q*8, &Bdb[buf][nh*8192 + s*8]);
        }
    };

    bf16x8 af[2][2];
    bf16x8 bfr[8];
    auto readA = [&](int ks, int buf){
        #pragma unroll
        for (int mf=0; mf<2; mf++){
            const int row = w*32 + mf*16 + (lane & 15);
            const int q = (ks*4 + (lane >> 4)) ^ (row & 7);
            af[ks][mf] = *(const bf16x8*)(&Adb[buf][row*64 + q*8]);
        }
    };
    auto readB = [&](int nh, int ks, int buf){
        #pragma unroll
        for (int nf=0; nf<8; nf++){
            const int row = nh*128 + nf*16 + (lane & 15);
            const int q = (ks*4 + (lane >> 4)) ^ (row & 7);
            bfr[nf] = *(const bf16x8*)(&Bdb[buf][row*64 + q*8]);
        }
    };
    auto mfma16 = [&](int nbase, int ks){
        __builtin_amdgcn_s_setprio(1);
        #pragma unroll
        for (int nf=0; nf<8; nf++)
            #pragma unroll
            for (int mf=0; mf<2; mf++)
                acc[mf][nbase+nf] = __builtin_amdgcn_mfma_f32_16x16x32_bf16(
                    af[ks][mf], bfr[nf], acc[mf][nbase+nf], 0,0,0);
        __builtin_amdgcn_s_setprio(0);
    };

    stageA(0, 0); stageBh(0, 0, 0); stageBh(0, 1, 0);

    int cur = 0;
    for (int kt = 0; kt < NT; ++kt){
        const int nb = cur ^ 1;
        const bool pre = (kt + 1 < NT);
        if (pre) asm volatile("s_waitcnt vmcnt(2)" ::: "memory");
        else     asm volatile("s_waitcnt vmcnt(0)" ::: "memory");
        __builtin_amdgcn_s_barrier();
        if (pre) stageA(kt+1, nb);
        readA(0, cur); readB(0, 0, cur);
        mfma16(0, 0);
        if (pre) asm volatile("s_waitcnt vmcnt(4)" ::: "memory");
        __builtin_amdgcn_s_barrier();
        if (pre) stageBh(kt+1, 0, nb);
        readB(1, 0, cur);
        mfma16(8, 0);
        __builtin_amdgcn_s_barrier();
        if (pre) stageBh(kt+1, 1, nb);
        readA(1, cur); readB(0, 1, cur);
        mfma16(0, 1);
        __builtin_amdgcn_s_barrier();
        readB(1, 1, cur);
        mfma16(8, 1);
        cur = nb;
    }

    // epilogue (C/D layout: col=lane&15, row=(lane>>4)*4+rj, m89-verified)
    if (EPI == 0){
        u16* out = (u16*)outv;
        #pragma unroll
        for (int mf=0; mf<2; mf++)
            #pragma unroll
            for (int g4=0; g4<4; g4++)
                #pragma unroll
                for (int nf2=0; nf2<2; nf2++){
                    const int na = g4*4 + nf2;
                    const int d  = (n0 >> 1) + g4*32 + nf2*16 + (lane & 15);
                    #pragma unroll
                    for (int rj=0; rj<4; rj++){
                        const int m = m0 + w*32 + mf*16 + (lane >> 4)*4 + rj;
                        float v = acc[mf][na][rj];
                        float g = acc[mf][na+2][rj];
                        v = v * (g / (1.f + __expf(-g)));
                        out[(size_t)m*DI + d] = f2bf(v);
                    }
                }
    } else if (EPI == 1){
        u16* out = (u16*)outv;
        if (n0 < 2048){
            #pragma unroll
            for (int mf=0; mf<2; mf++)
                #pragma unroll
                for (int na=0; na<16; na++){
                    const int col = n0 + na*16 + (lane & 15);
                    u16x4 o;
                    #pragma unroll
                    for (int rj=0; rj<4; rj++){
                        float z = acc[mf][na][rj] + bias[col];
                        float v = (z > 20.f) ? z : log1pf(__expf(z));
                        o[rj] = f2bf(v);
                    }
                    const int rb = m0 + w*32 + mf*16 + (lane >> 4)*4;
                    const int bb = rb >> 12;
                    const int l  = rb & (LL-1);
                    *(u16x4*)(out + ((size_t)bb*DI + col)*LL + l) = o;
                }
        } else {
            // BC tail: cols 2048..2175 -> interleaved f32 [t][n2][{B,C}]
            #pragma unroll
            for (int mf=0; mf<2; mf++)
                #pragma unroll
                for (int na=0; na<8; na++){
                    const int n2 = na*16 + (lane & 15);      // 0..127
                    #pragma unroll
                    for (int rj=0; rj<4; rj++){
                        const int row = m0 + w*32 + mf*16 + (lane >> 4)*4 + rj;
                        bcout[((size_t)row*64 + (n2 & 63))*2 + (n2 >> 6)] = acc[mf][na][rj];
                    }
                }
        }
    } else {
        float* out = (float*)outv;
        #pragma unroll
        for (int mf=0; mf<2; mf++)
            #pragma unroll
            for (int na=0; na<16; na++){
                const int col = n0 + na*16 + (lane & 15);
                #pragma unroll
                for (int rj=0; rj<4; rj++){
                    const int m = m0 + w*32 + mf*16 + (lane >> 4)*4 + rj;
                    out[(size_t)m*N + col] = acc[mf][na][rj];
                }
            }
    }
}

// =====================================================================
// Fused causal depthwise conv1d (+bias) + RMSNorm. bf16 in/out, fp32 math.
// =====================================================================
__global__ __launch_bounds__(256)
void conv_rms(const u16* __restrict__ xin, const float* __restrict__ cw,
              const float* __restrict__ cb, const float* __restrict__ nw,
              u16* __restrict__ xc)
{
    const int bl  = blockIdx.x;
    const int l   = bl & (LL-1);
    const int tid = threadIdx.x;
    const int d0  = tid * 8;

    float a[8];
    #pragma unroll
    for (int j=0;j<8;j++) a[j] = cb[d0+j];
    #pragma unroll
    for (int t=0;t<4;t++){
        const int ls = l - 3 + t;
        if (ls >= 0){
            bf16x8 xv = *(const bf16x8*)(xin + (size_t)(bl-3+t)*DI + d0);
            #pragma unroll
            for (int j=0;j<8;j++)
                a[j] += bf2f((u16)xv[j]) * cw[(d0+j)*4 + t];
        }
    }
    float ss = 0.f;
    #pragma unroll
    for (int j=0;j<8;j++) ss += a[j]*a[j];
    ss += __shfl_xor(ss,32); ss += __shfl_xor(ss,16); ss += __shfl_xor(ss,8);
    ss += __shfl_xor(ss,4);  ss += __shfl_xor(ss,2);  ss += __shfl_xor(ss,1);
    __shared__ float red[4];
    if ((tid & 63)==0) red[tid>>6] = ss;
    __syncthreads();
    const float tot   = red[0]+red[1]+red[2]+red[3];
    const float scale = rsqrtf(tot * (1.f/DI) + EPSF);
    u16x4 o0, o1;
    #pragma unroll
    for (int j=0;j<4;j++) o0[j] = f2bf(a[j]  *scale*nw[d0+j]);
    #pragma unroll
    for (int j=0;j<4;j++) o1[j] = f2bf(a[4+j]*scale*nw[d0+4+j]);
    *(u16x4*)(xc + (size_t)bl*DI + d0)     = o0;
    *(u16x4*)(xc + (size_t)bl*DI + d0 + 4) = o1;
}

// =====================================================================
// Tiled bf16 transpose (per batch b = blockIdx.z): in [R][C] -> out [C][R]
// =====================================================================
__global__ __launch_bounds__(256)
void transpose_bf(const u16* __restrict__ in, u16* __restrict__ out, int R, int C)
{
    __shared__ u16 t[32][36];
    const int b  = blockIdx.z;
    const int r0 = blockIdx.y * 32;
    const int c0 = blockIdx.x * 32;
    const int ir = threadIdx.x >> 3;
    const int ic = (threadIdx.x & 7) * 4;
    const size_t base = (size_t)b * R * C;

    u16x4 v = *(const u16x4*)(in + base + (size_t)(r0+ir)*C + c0 + ic);
    #pragma unroll
    for (int k=0;k<4;k++) t[ir][ic+k] = v[k];
    __syncthreads();
    u16x4 o;
    #pragma unroll
    for (int k=0;k<4;k++) o[k] = t[ic+k][ir];
    *(u16x4*)(out + base + (size_t)(c0+ir)*R + r0 + ic) = o;
}

// =====================================================================
// Selective scan v9b = r12's scan9 + next-tile dt/xc register prefetch
// (removes per-tile load->dtu-write VMEM stall; inst count unchanged).
// =====================================================================
#define BSTAGE(MU) \
    { _Pragma("unroll") \
      for (int i=0;i<MU;i++){ \
          const bool g = (lane & MU) != 0; \
          float q = g ? p[i] : p[i+MU]; \
          float r = __shfl_xor(q, MU); \
          p[i] = (g ? p[i+MU] : p[i]) + r; \
      } }

__global__ __launch_bounds__(512)
void scan9(const u16* __restrict__ dtT, const u16* __restrict__ xcT,
           const float* __restrict__ BCi, const float* __restrict__ A_log,
           const float* __restrict__ Dp, u16* __restrict__ yT)
{
    __shared__ float lbc[2][64*128];       // [buf][t(64)][n(64)][{B,C}]
    __shared__ float dtu[8][64][2];        // wave-private (dt, dt*x) per step
    const int tid  = threadIdx.x;
    const int lane = tid & 63;
    const int wave = tid >> 6;             // 0..7
    const int b    = blockIdx.x >> 8;      // 256 blocks per batch
    const int d    = (blockIdx.x & 255) * 8 + wave;

    const float Ac = -__expf(A_log[d*NS + lane]) * LOG2E;
    const float Dd = Dp[d];
    const size_t chbase = ((size_t)b*DI + d) * LL;
    const u16* dtp = dtT + chbase;
    const u16* xcp = xcT + chbase;
    u16*       yp  = yT  + chbase;
    const float* bcb = BCi + (size_t)b * LL * 128;

    auto stage = [&](int t0, int bufi){
        const float* src = bcb + (size_t)t0 * 128;
        #pragma unroll
        for (int i=0;i<4;i++){
            const int slot = i*512 + wave*64;          // wave-uniform
            gload16(src + (size_t)(slot + lane)*4, &lbc[bufi][slot*4]);
        }
    };

    stage(0, 0);
    float dtL = bf2f(dtp[lane]);
    float xcL = bf2f(xcp[lane]);
    asm volatile("s_waitcnt vmcnt(0)" ::: "memory");
    __syncthreads();

    float h = 0.f;
    int cur = 0;
    for (int t0 = 0; t0 < LL; t0 += 64) {
        const bool more = (t0 + 64 < LL);
        if (more) stage(t0 + 64, cur ^ 1);
        // prefetch next tile's dt/xc into regs (used NEXT iter; waited by
        // the trailing vmcnt(0))
        float dtN = 0.f, xcN = 0.f;
        if (more) { dtN = bf2f(dtp[t0 + 64 + lane]); xcN = bf2f(xcp[t0 + 64 + lane]); }

        // current tile's (dt, dt*x) already in regs -> no VMEM stall
        *(float2*)&dtu[wave][lane][0] = make_float2(dtL, dtL * xcL);
        const float* lb = lbc[cur];
        const float* dub = &dtu[wave][0][0];

        float p[64];
        #pragma unroll
        for (int j=0;j<64;j++){
            const float2 du = *(const float2*)(dub + j*2);       // uniform addr
            const float2 bc = *(const float2*)(lb + (j*64 + lane)*2);
            const float a   = exp2f(du.x * Ac);
            h = a*h + du.y*bc.x;
            p[j] = h * bc.y;
        }
        #pragma unroll
        for (int i=0;i<32;i++){
            float a0 = p[i], b0 = p[i+32];
            asm("v_permlane32_swap_b32 %0, %1" : "+v"(a0), "+v"(b0));
            p[i] = a0 + b0;
        }
        BSTAGE(16) BSTAGE(8) BSTAGE(4) BSTAGE(2) BSTAGE(1)
        {
            float yv = p[0] + Dd * xcL;
            unsigned pk;
            asm("v_cvt_pk_bf16_f32 %0, %1, %2" : "=v"(pk) : "v"(yv), "v"(yv));
            yp[t0 + lane] = (u16)pk;
        }

        asm volatile("s_waitcnt vmcnt(0)" ::: "memory");
        __syncthreads();
        dtL = dtN; xcL = xcN;
        cur ^= 1;
    }
}

// =====================================================================
// Workspace layout (u16 element offsets; total ~118.3 MB, <138 proven):
//   [0        ,  8388608)  x_bf   \
//   [8388608  , 16777216)  ip_bf  / -> xcT_bf [0,16777216)
//   [16777216 , 20971520)  dtw_bf \  adjacent: merged W for gemm256<1>
//   [20971520 , 21495808)  bcw_bf /  (256 rows; rows 128+ = inert garbage)
//   [21495808 , 38273024)  xin_bf -> dtT_bf -> y_bf
//   [38273024 , 55050240)  xc_bf  -> yT_bf
//   [55050240 , ...     )  BC f32 [M*128] interleaved, then ow_bf [DM*DI]
// =====================================================================
extern "C" void kernel_launch(void* const* d_in, const int* in_sizes, int n_in,
                              void* d_out, int out_size, void* d_ws, size_t ws_size,
                              hipStream_t stream) {
    const float* x       = (const float*)d_in[0];
    const float* in_proj = (const float*)d_in[1];
    const float* conv_w  = (const float*)d_in[2];
    const float* conv_b  = (const float*)d_in[3];
    const float* norm_w  = (const float*)d_in[4];
    const float* dt_w    = (const float*)d_in[5];
    const float* dt_b    = (const float*)d_in[6];
    const float* A_log   = (const float*)d_in[7];
    const float* Dp      = (const float*)d_in[8];
    const float* B_w     = (const float*)d_in[9];
    const float* C_w     = (const float*)d_in[10];
    const float* out_w   = (const float*)d_in[11];

    const int M = BB * LL;                        // 8192
    u16* wsu = (u16*)d_ws;
    u16*   x_bf   = wsu;                              // M*DM
    u16*   ip_bf  = wsu + (size_t)M*DM;               // 2*DI*DM (permuted W')
    u16*   dtw_bf = ip_bf + (size_t)2*DI*DM;          // DI*DI
    u16*   bcw_bf = dtw_bf + (size_t)DI*DI;           // 256*DI (128 live rows)
    u16*   xin_bf = bcw_bf + (size_t)256*DI;          // M*DI
    u16*   xc_bf  = xin_bf + (size_t)M*DI;            // M*DI
    float* BC     = (float*)(xc_bf + (size_t)M*DI);   // M*128 f32 (interleaved)
    u16*   ow_bf  = (u16*)(BC + (size_t)M*128);       // DM*DI
    // overlays (liveness-checked):
    u16*   dtT_bf = xin_bf;   // gemm256<1> out (xin dead after conv)
    u16*   xcT_bf = x_bf;     // transpose-xc out (x/ip dead)
    u16*   yT_bf  = xc_bf;    // scan out (xc dead after transpose-xc)
    u16*   y_bf   = xin_bf;   // transpose-y out (dtT dead after scan)

    // 0) all fp32 -> bf16 converts in one launch (ip permuted for gate pairing)
    cvt_all<<<18688, 256, 0, stream>>>(x, in_proj, dt_w, B_w, C_w, out_w,
                                       x_bf, ip_bf, dtw_bf, bcw_bf,
                                       bcw_bf + (size_t)NS*DI, ow_bf);

    // 1) xin = (x@Wx^T)*silu(x@Wg^T) via 256^2 pipeline, gate fused (W')
    gemm256<0><<<dim3(2*DI/256, M/256), 512, 0, stream>>>(
        x_bf, ip_bf, nullptr, xin_bf, nullptr, M, 2*DI, DM);

    // 2) causal depthwise conv + RMSNorm -> bf16 xc [M, DI]
    conv_rms<<<M, 256, 0, stream>>>(xin_bf, conv_w, conv_b, norm_w, xc_bf);

    // 3) merged dt|BC: softplus->dtT (cols<2048), BC f32 (cols 2048-2175)
    gemm256<1><<<dim3(2304/256, M/256), 512, 0, stream>>>(
        xc_bf, dtw_bf, dt_b, dtT_bf, BC, M, 2304, DI);

    // 4) transpose xc to time-minor (into dead x/ip region)
    transpose_bf<<<dim3(DI/32, LL/32, BB), 256, 0, stream>>>(xc_bf, xcT_bf, LL, DI);

    // 5) selective scan -> yT bf16 [b, d, L] (over dead xc)
    scan9<<<BB*DI/8, 512, 0, stream>>>(dtT_bf, xcT_bf, BC, A_log, Dp, yT_bf);

    // 6) yT -> y bf16 [M, DI] (over dead dtT)
    transpose_bf<<<dim3(LL/32, DI/32, BB), 256, 0, stream>>>(yT_bf, y_bf, DI, LL);

    // 7) out = y @ out_w^T -> f32 [M, DM] via 256^2 pipeline
    gemm256<2><<<dim3(DM/256, M/256), 512, 0, stream>>>(
        y_bf, ow_bf, nullptr, (float*)d_out, nullptr, M, DM, DI);
}

// Round 19
// 931.357 us; speedup vs baseline: 1.1189x; 1.1189x over previous
//
#include <hip/hip_runtime.h>
#include <cmath>

#define BB 2
#define LL 4096
#define DM 1024
#define DI 2048
#define NS 64
static constexpr float EPSF  = 1.1920928955078125e-07f; // float32 eps
static constexpr float LOG2E = 1.4426950408889634f;

typedef unsigned short u16;
typedef __attribute__((ext_vector_type(4))) unsigned short u16x4;
typedef __attribute__((ext_vector_type(8))) short bf16x8;
typedef __attribute__((ext_vector_type(4))) float f32x4;

__device__ __forceinline__ u16 f2bf(float f){
    unsigned u = __float_as_uint(f);
    return (u16)((u + 0x7fffu + ((u >> 16) & 1u)) >> 16);   // RNE
}
__device__ __forceinline__ float bf2f(u16 h){ return __uint_as_float(((unsigned)h) << 16); }
__device__ __forceinline__ void gload16(const void* g, void* l){
    __builtin_amdgcn_global_load_lds((const __attribute__((address_space(1))) void*)g,
                                     (__attribute__((address_space(3))) void*)l, 16, 0, 0);
}

// =====================================================================
// Fused fp32->bf16 convert. ip segment is PERMUTED: W'[r] interleaves
// x-rows and gate-rows in 32-row groups (gate pairing in gemm256<0>).
// Segments (vec4 units): x 2097152 | ip 1048576 | dtw 1048576 |
//   B_w 32768 | C_w 32768 | ow 524288
// =====================================================================
__global__ __launch_bounds__(256)
void cvt_all(const float* __restrict__ s0, const float* __restrict__ s1,
             const float* __restrict__ s2, const float* __restrict__ s3,
             const float* __restrict__ s4, const float* __restrict__ s5,
             u16* __restrict__ d0, u16* __restrict__ d1, u16* __restrict__ d2,
             u16* __restrict__ d3, u16* __restrict__ d4, u16* __restrict__ d5)
{
    size_t v = (size_t)blockIdx.x * 256 + threadIdx.x;   // vec4 index
    const float* src; u16* dst; size_t off;
    int seg;
    if      (v < 2097152u){ src=s0; dst=d0; off=v; seg=0; }
    else if (v < 3145728u){ src=s1; dst=d1; off=v-2097152u; seg=1; }
    else if (v < 4194304u){ src=s2; dst=d2; off=v-3145728u; seg=2; }
    else if (v < 4227072u){ src=s3; dst=d3; off=v-4194304u; seg=3; }
    else if (v < 4259840u){ src=s4; dst=d4; off=v-4227072u; seg=4; }
    else                  { src=s5; dst=d5; off=v-4259840u; seg=5; }
    size_t i = off*4;
    size_t isrc = i;
    if (seg == 1){
        // dst row r -> src row s (32-row x/gate interleave)
        size_t r = i >> 10, c = i & 1023;
        size_t g = r >> 6, w6 = r & 63;
        size_t s = (w6 < 32) ? (g*32 + w6) : (2048 + g*32 + (w6 - 32));
        isrc = s*1024 + c;
    }
    float4 x = *(const float4*)(src+isrc);
    u16x4 o; o[0]=f2bf(x.x); o[1]=f2bf(x.y); o[2]=f2bf(x.z); o[3]=f2bf(x.w);
    *(u16x4*)(dst+i) = o;
}

// =====================================================================
// 256x256 / BK=64 deep-pipelined GEMM (T2 swizzle, T3+T4 counted vmcnt,
// T5 setprio, raw s_barrier). 512 thr = 8 waves as 8M x 1N.
// EPI 0: silu-gate (W' interleaved) -> bf16 xin [M, N/2]
// EPI 1: softplus+bias -> bf16 dtT[b][col][l] time-minor.
// =====================================================================
template<int EPI>
__global__ __launch_bounds__(512)
void gemm256(const u16* __restrict__ A, const u16* __restrict__ W,
             const float* __restrict__ bias, u16* __restrict__ out,
             int M, int N, int K)
{
    __shared__ u16 Adb[2][256*64];
    __shared__ u16 Bdb[2][256*64];
    const int tid  = threadIdx.x;
    const int lane = tid & 63;
    const int w    = tid >> 6;
    const int n0 = blockIdx.x * 256;
    const int m0 = blockIdx.y * 256;
    const int NT = K >> 6;

    f32x4 acc[2][16];
    #pragma unroll
    for (int mf=0; mf<2; mf++)
        #pragma unroll
        for (int nf=0; nf<16; nf++)
            #pragma unroll
            for (int r=0;r<4;r++) acc[mf][nf][r] = 0.f;

    auto stageA = [&](int kt, int buf){
        const int k0 = kt << 6;
        #pragma unroll
        for (int i=0;i<4;i++){
            const int s = i*512 + tid;
            const int row = s >> 3;
            const int q = (s & 7) ^ (row & 7);
            gload16(A + (size_t)(m0+row)*K + k0 + q*8, &Adb[buf][s*8]);
        }
    };
    auto stageBh = [&](int kt, int nh, int buf){
        const int k0 = kt << 6;
        #pragma unroll
        for (int i=0;i<2;i++){
            const int s = i*512 + tid;
            const int row = nh*128 + (s >> 3);
            const int q = (s & 7) ^ (row & 7);
            gload16(W + (size_t)(n0+row)*K + k0 + q*8, &Bdb[buf][nh*8192 + s*8]);
        }
    };

    bf16x8 af[2][2];   // [ks][mf], persists across the tile's phases
    bf16x8 bfr[8];
    auto readA = [&](int ks, int buf){
        #pragma unroll
        for (int mf=0; mf<2; mf++){
            const int row = w*32 + mf*16 + (lane & 15);
            const int q = (ks*4 + (lane >> 4)) ^ (row & 7);
            af[ks][mf] = *(const bf16x8*)(&Adb[buf][row*64 + q*8]);
        }
    };
    auto readB = [&](int nh, int ks, int buf){
        #pragma unroll
        for (int nf=0; nf<8; nf++){
            const int row = nh*128 + nf*16 + (lane & 15);
            const int q = (ks*4 + (lane >> 4)) ^ (row & 7);
            bfr[nf] = *(const bf16x8*)(&Bdb[buf][row*64 + q*8]);
        }
    };
    auto mfma16 = [&](int nbase, int ks){
        __builtin_amdgcn_s_setprio(1);
        #pragma unroll
        for (int nf=0; nf<8; nf++)
            #pragma unroll
            for (int mf=0; mf<2; mf++)
                acc[mf][nbase+nf] = __builtin_amdgcn_mfma_f32_16x16x32_bf16(
                    af[ks][mf], bfr[nf], acc[mf][nbase+nf], 0,0,0);
        __builtin_amdgcn_s_setprio(0);
    };

    // prologue: stage tile 0
    stageA(0, 0); stageBh(0, 0, 0); stageBh(0, 1, 0);

    int cur = 0;
    for (int kt = 0; kt < NT; ++kt){
        const int nb = cur ^ 1;
        const bool pre = (kt + 1 < NT);
        // ---- ph0: Nh0, ks0 ----
        if (pre) asm volatile("s_waitcnt vmcnt(2)" ::: "memory");
        else     asm volatile("s_waitcnt vmcnt(0)" ::: "memory");
        __builtin_amdgcn_s_barrier();
        if (pre) stageA(kt+1, nb);
        readA(0, cur); readB(0, 0, cur);
        mfma16(0, 0);
        // ---- ph1: Nh1, ks0 ----
        if (pre) asm volatile("s_waitcnt vmcnt(4)" ::: "memory");
        __builtin_amdgcn_s_barrier();
        if (pre) stageBh(kt+1, 0, nb);
        readB(1, 0, cur);
        mfma16(8, 0);
        // ---- ph2: Nh0, ks1 ----
        __builtin_amdgcn_s_barrier();
        if (pre) stageBh(kt+1, 1, nb);
        readA(1, cur); readB(0, 1, cur);
        mfma16(0, 1);
        // ---- ph3: Nh1, ks1 ----
        __builtin_amdgcn_s_barrier();
        readB(1, 1, cur);
        mfma16(8, 1);
        cur = nb;
    }

    // epilogue (C/D layout: col=lane&15, row=(lane>>4)*4+rj, m89-verified)
    if (EPI == 0){
        // gate: W' 32-row interleave -> pair (na, na+2) within each 64-group
        #pragma unroll
        for (int mf=0; mf<2; mf++)
            #pragma unroll
            for (int g4=0; g4<4; g4++)
                #pragma unroll
                for (int nf2=0; nf2<2; nf2++){
                    const int na = g4*4 + nf2;
                    const int d  = (n0 >> 1) + g4*32 + nf2*16 + (lane & 15);
                    #pragma unroll
                    for (int rj=0; rj<4; rj++){
                        const int m = m0 + w*32 + mf*16 + (lane >> 4)*4 + rj;
                        float v = acc[mf][na][rj];
                        float g = acc[mf][na+2][rj];
                        v = v * (g / (1.f + __expf(-g)));
                        out[(size_t)m*DI + d] = f2bf(v);
                    }
                }
    } else {
        // softplus + bias -> dtT[b][col][l], 4 consecutive l per store
        #pragma unroll
        for (int mf=0; mf<2; mf++)
            #pragma unroll
            for (int na=0; na<16; na++){
                const int col = n0 + na*16 + (lane & 15);
                u16x4 o;
                #pragma unroll
                for (int rj=0; rj<4; rj++){
                    float z = acc[mf][na][rj] + bias[col];
                    float v = (z > 20.f) ? z : log1pf(__expf(z));
                    o[rj] = f2bf(v);
                }
                const int rb = m0 + w*32 + mf*16 + (lane >> 4)*4;
                const int bb = rb >> 12;
                const int l  = rb & (LL-1);
                *(u16x4*)(out + ((size_t)bb*DI + col)*LL + l) = o;
            }
    }
}

// =====================================================================
// OLD 128x128 GEMM (proven m97 structure). MODE 0: plain f32 out (G8).
// MODE 3: f32 out interleaved BC[t][n][{B,C}] (N must be 128).
// =====================================================================
template<int MODE>
__global__ __launch_bounds__(256)
void gemm_bf16(const u16* __restrict__ A, const u16* __restrict__ W,
               void* __restrict__ Cout, int M, int N, int K)
{
    __shared__ u16 As[128*32];
    __shared__ u16 Bs[128*32];

    const int tid  = threadIdx.x;
    const int lane = tid & 63;
    const int wave = tid >> 6;
    const int m0 = blockIdx.y * 128;
    const int n0 = blockIdx.x * 128;
    const int wr = wave >> 1, wc = wave & 1;

    f32x4 acc[4][4];
    #pragma unroll
    for (int i=0;i<4;i++)
        #pragma unroll
        for (int j=0;j<4;j++)
            #pragma unroll
            for (int r=0;r<4;r++) acc[i][j][r] = 0.f;

    for (int k0 = 0; k0 < K; k0 += 32) {
        #pragma unroll
        for (int it = 0; it < 2; ++it) {
            const int s  = it*256 + tid;
            const int r  = s >> 2;
            const int q  = s & 3;
            const int qs = q ^ ((r >> 1) & 3);
            const int ub = (it*256 + wave*64) * 8;
            gload16(A + (size_t)(m0 + r)*K + k0 + qs*8, As + ub);
            gload16(W + (size_t)(n0 + r)*K + k0 + qs*8, Bs + ub);
        }
        __syncthreads();

        bf16x8 af[4], bfr[4];
        #pragma unroll
        for (int mi=0; mi<4; ++mi){
            const int r  = wr*64 + mi*16 + (lane & 15);
            const int qs = (lane >> 4) ^ ((r >> 1) & 3);
            af[mi] = *(const bf16x8*)(As + (r*4 + qs)*8);
        }
        #pragma unroll
        for (int ni=0; ni<4; ++ni){
            const int c  = wc*64 + ni*16 + (lane & 15);
            const int qs = (lane >> 4) ^ ((c >> 1) & 3);
            bfr[ni] = *(const bf16x8*)(Bs + (c*4 + qs)*8);
        }
        #pragma unroll
        for (int mi=0; mi<4; ++mi)
            #pragma unroll
            for (int ni=0; ni<4; ++ni)
                acc[mi][ni] = __builtin_amdgcn_mfma_f32_16x16x32_bf16(af[mi], bfr[ni], acc[mi][ni], 0,0,0);
        __syncthreads();
    }

    #pragma unroll
    for (int mi=0; mi<4; ++mi){
        #pragma unroll
        for (int ni=0; ni<4; ++ni){
            const int col = n0 + wc*64 + ni*16 + (lane & 15);
            #pragma unroll
            for (int rj=0; rj<4; ++rj){
                const int row = m0 + wr*64 + mi*16 + (lane >> 4)*4 + rj;
                float v = acc[mi][ni][rj];
                if (MODE==3)
                    ((float*)Cout)[((size_t)row*64 + (col & 63))*2 + (col >> 6)] = v;
                else
                    ((float*)Cout)[(size_t)row*N + col] = v;
            }
        }
    }
}

// =====================================================================
// Fused causal depthwise conv1d (+bias) + RMSNorm. bf16 in/out, fp32 math.
// =====================================================================
__global__ __launch_bounds__(256)
void conv_rms(const u16* __restrict__ xin, const float* __restrict__ cw,
              const float* __restrict__ cb, const float* __restrict__ nw,
              u16* __restrict__ xc)
{
    const int bl  = blockIdx.x;
    const int l   = bl & (LL-1);
    const int tid = threadIdx.x;
    const int d0  = tid * 8;

    float a[8];
    #pragma unroll
    for (int j=0;j<8;j++) a[j] = cb[d0+j];
    #pragma unroll
    for (int t=0;t<4;t++){
        const int ls = l - 3 + t;
        if (ls >= 0){
            bf16x8 xv = *(const bf16x8*)(xin + (size_t)(bl-3+t)*DI + d0);
            #pragma unroll
            for (int j=0;j<8;j++)
                a[j] += bf2f((u16)xv[j]) * cw[(d0+j)*4 + t];
        }
    }
    float ss = 0.f;
    #pragma unroll
    for (int j=0;j<8;j++) ss += a[j]*a[j];
    ss += __shfl_xor(ss,32); ss += __shfl_xor(ss,16); ss += __shfl_xor(ss,8);
    ss += __shfl_xor(ss,4);  ss += __shfl_xor(ss,2);  ss += __shfl_xor(ss,1);
    __shared__ float red[4];
    if ((tid & 63)==0) red[tid>>6] = ss;
    __syncthreads();
    const float tot   = red[0]+red[1]+red[2]+red[3];
    const float scale = rsqrtf(tot * (1.f/DI) + EPSF);
    u16x4 o0, o1;
    #pragma unroll
    for (int j=0;j<4;j++) o0[j] = f2bf(a[j]  *scale*nw[d0+j]);
    #pragma unroll
    for (int j=0;j<4;j++) o1[j] = f2bf(a[4+j]*scale*nw[d0+4+j]);
    *(u16x4*)(xc + (size_t)bl*DI + d0)     = o0;
    *(u16x4*)(xc + (size_t)bl*DI + d0 + 4) = o1;
}

// =====================================================================
// Tiled bf16 transpose (per batch b = blockIdx.z): in [R][C] -> out [C][R]
// =====================================================================
__global__ __launch_bounds__(256)
void transpose_bf(const u16* __restrict__ in, u16* __restrict__ out, int R, int C)
{
    __shared__ u16 t[32][36];
    const int b  = blockIdx.z;
    const int r0 = blockIdx.y * 32;
    const int c0 = blockIdx.x * 32;
    const int ir = threadIdx.x >> 3;
    const int ic = (threadIdx.x & 7) * 4;
    const size_t base = (size_t)b * R * C;

    u16x4 v = *(const u16x4*)(in + base + (size_t)(r0+ir)*C + c0 + ic);
    #pragma unroll
    for (int k=0;k<4;k++) t[ir][ic+k] = v[k];
    __syncthreads();
    u16x4 o;
    #pragma unroll
    for (int k=0;k<4;k++) o[k] = t[ic+k][ir];
    *(u16x4*)(out + base + (size_t)(c0+ir)*R + r0 + ic) = o;
}

// =====================================================================
// Selective scan v9b = proven scan9 + next-tile dt/xc register prefetch
// (r18-verified: 462 -> 458 us).
// =====================================================================
#define BSTAGE(MU) \
    { _Pragma("unroll") \
      for (int i=0;i<MU;i++){ \
          const bool g = (lane & MU) != 0; \
          float q = g ? p[i] : p[i+MU]; \
          float r = __shfl_xor(q, MU); \
          p[i] = (g ? p[i+MU] : p[i]) + r; \
      } }

__global__ __launch_bounds__(512)
void scan9(const u16* __restrict__ dtT, const u16* __restrict__ xcT,
           const float* __restrict__ BCi, const float* __restrict__ A_log,
           const float* __restrict__ Dp, u16* __restrict__ yT)
{
    __shared__ float lbc[2][64*128];       // [buf][t(64)][n(64)][{B,C}]
    __shared__ float dtu[8][64][2];        // wave-private (dt, dt*x) per step
    const int tid  = threadIdx.x;
    const int lane = tid & 63;
    const int wave = tid >> 6;             // 0..7
    const int b    = blockIdx.x >> 8;      // 256 blocks per batch
    const int d    = (blockIdx.x & 255) * 8 + wave;

    const float Ac = -__expf(A_log[d*NS + lane]) * LOG2E;
    const float Dd = Dp[d];
    const size_t chbase = ((size_t)b*DI + d) * LL;
    const u16* dtp = dtT + chbase;
    const u16* xcp = xcT + chbase;
    u16*       yp  = yT  + chbase;
    const float* bcb = BCi + (size_t)b * LL * 128;

    auto stage = [&](int t0, int bufi){
        const float* src = bcb + (size_t)t0 * 128;
        #pragma unroll
        for (int i=0;i<4;i++){
            const int slot = i*512 + wave*64;          // wave-uniform
            gload16(src + (size_t)(slot + lane)*4, &lbc[bufi][slot*4]);
        }
    };

    stage(0, 0);
    float dtL = bf2f(dtp[lane]);
    float xcL = bf2f(xcp[lane]);
    asm volatile("s_waitcnt vmcnt(0)" ::: "memory");
    __syncthreads();

    float h = 0.f;
    int cur = 0;
    for (int t0 = 0; t0 < LL; t0 += 64) {
        const bool more = (t0 + 64 < LL);
        if (more) stage(t0 + 64, cur ^ 1);
        // prefetch next tile's dt/xc into regs (used NEXT iter; covered by
        // the trailing vmcnt(0))
        float dtN = 0.f, xcN = 0.f;
        if (more) { dtN = bf2f(dtp[t0 + 64 + lane]); xcN = bf2f(xcp[t0 + 64 + lane]); }

        // current tile's (dt, dt*x) already in regs -> no VMEM stall
        *(float2*)&dtu[wave][lane][0] = make_float2(dtL, dtL * xcL);
        const float* lb = lbc[cur];
        const float* dub = &dtu[wave][0][0];

        float p[64];
        #pragma unroll
        for (int j=0;j<64;j++){
            const float2 du = *(const float2*)(dub + j*2);       // uniform addr
            const float2 bc = *(const float2*)(lb + (j*64 + lane)*2);
            const float a   = exp2f(du.x * Ac);
            h = a*h + du.y*bc.x;
            p[j] = h * bc.y;
        }
        #pragma unroll
        for (int i=0;i<32;i++){
            float a0 = p[i], b0 = p[i+32];
            asm("v_permlane32_swap_b32 %0, %1" : "+v"(a0), "+v"(b0));
            p[i] = a0 + b0;
        }
        BSTAGE(16) BSTAGE(8) BSTAGE(4) BSTAGE(2) BSTAGE(1)
        {
            float yv = p[0] + Dd * xcL;
            unsigned pk;
            asm("v_cvt_pk_bf16_f32 %0, %1, %2" : "=v"(pk) : "v"(yv), "v"(yv));
            yp[t0 + lane] = (u16)pk;
        }

        asm volatile("s_waitcnt vmcnt(0)" ::: "memory");
        __syncthreads();
        dtL = dtN; xcL = xcN;
        cur ^= 1;
    }
}

// =====================================================================
// Workspace layout: identical to r17 (proven-safe).
// =====================================================================
extern "C" void kernel_launch(void* const* d_in, const int* in_sizes, int n_in,
                              void* d_out, int out_size, void* d_ws, size_t ws_size,
                              hipStream_t stream) {
    const float* x       = (const float*)d_in[0];
    const float* in_proj = (const float*)d_in[1];
    const float* conv_w  = (const float*)d_in[2];
    const float* conv_b  = (const float*)d_in[3];
    const float* norm_w  = (const float*)d_in[4];
    const float* dt_w    = (const float*)d_in[5];
    const float* dt_b    = (const float*)d_in[6];
    const float* A_log   = (const float*)d_in[7];
    const float* Dp      = (const float*)d_in[8];
    const float* B_w     = (const float*)d_in[9];
    const float* C_w     = (const float*)d_in[10];
    const float* out_w   = (const float*)d_in[11];

    const int M = BB * LL;                        // 8192
    u16* wsu = (u16*)d_ws;
    u16*   x_bf   = wsu;                              // M*DM
    u16*   ip_bf  = wsu + (size_t)M*DM;               // 2*DI*DM (permuted W')
    u16*   dtw_bf = ip_bf + (size_t)2*DI*DM;          // DI*DI
    u16*   bcw_bf = dtw_bf + (size_t)DI*DI;           // 128*DI
    u16*   xin_bf = bcw_bf + (size_t)128*DI;          // M*DI
    u16*   xc_bf  = xin_bf + (size_t)M*DI;            // M*DI
    float* BC     = (float*)(xc_bf + (size_t)M*DI);   // M*128 f32 (interleaved)
    u16*   ow_bf  = (u16*)(BC + (size_t)M*128);       // DM*DI
    // overlays (liveness-checked):
    u16*   dtT_bf = xin_bf;   // gemm256<1> out (xin dead after conv)
    u16*   xcT_bf = x_bf;     // transpose-xc out (x/ip/dtw dead)
    u16*   yT_bf  = xc_bf;    // scan out (xc dead after transpose-xc)
    u16*   y_bf   = xin_bf;   // transpose-y out (dtT dead after scan)

    // 0) all fp32 -> bf16 converts in one launch (ip permuted for gate pairing)
    cvt_all<<<18688, 256, 0, stream>>>(x, in_proj, dt_w, B_w, C_w, out_w,
                                       x_bf, ip_bf, dtw_bf, bcw_bf,
                                       bcw_bf + (size_t)NS*DI, ow_bf);

    // 1) xin = (x@Wx^T)*silu(x@Wg^T) via 256^2 pipeline, gate fused (W')
    gemm256<0><<<dim3(2*DI/256, M/256), 512, 0, stream>>>(
        x_bf, ip_bf, nullptr, xin_bf, M, 2*DI, DM);

    // 2) causal depthwise conv + RMSNorm -> bf16 xc [M, DI]
    conv_rms<<<M, 256, 0, stream>>>(xin_bf, conv_w, conv_b, norm_w, xc_bf);

    // 3a) dt = softplus(xc@dt_w^T+dt_b) -> dtT bf16 time-minor (256^2 pipeline)
    gemm256<1><<<dim3(DI/256, M/256), 512, 0, stream>>>(
        xc_bf, dtw_bf, dt_b, dtT_bf, M, DI, DI);

    // 3b) BC = xc @ [B_w;C_w]^T -> f32 interleaved [t][n][{B,C}] (old 128^2)
    gemm_bf16<3><<<dim3(1, M/128), 256, 0, stream>>>(
        xc_bf, bcw_bf, BC, M, 128, DI);

    // 4) transpose xc to time-minor (into dead x/ip region)
    transpose_bf<<<dim3(DI/32, LL/32, BB), 256, 0, stream>>>(xc_bf, xcT_bf, LL, DI);

    // 5) selective scan -> yT bf16 [b, d, L] (over dead xc)
    scan9<<<BB*DI/8, 512, 0, stream>>>(dtT_bf, xcT_bf, BC, A_log, Dp, yT_bf);

    // 6) yT -> y bf16 [M, DI] (over dead dtT)
    transpose_bf<<<dim3(LL/32, DI/32, BB), 256, 0, stream>>>(yT_bf, y_bf, DI, LL);

    // 7) out = y @ out_w^T -> f32 [M, DM] (old 128^2)
    gemm_bf16<0><<<dim3(DM/128, M/128), 256, 0, stream>>>(
        y_bf, ow_bf, (float*)d_out, M, DM, DI);
}